// Round 11
// baseline (283.071 us; speedup 1.0000x reference)
//
#include <hip/hip_runtime.h>
#include <hip/hip_bf16.h>
#include <stdint.h>

#define NE    64
#define DIN   512
#define DOUT  512
#define TTOK  131072
#define BM    128
#define BN    256
#define BK    32
#define NK    (DIN / BK)              // 16 K-steps
#define TILES_TOTAL (TTOK / BM + NE)  // 1088
#define NXCD  8
#define TPX   (TILES_TOTAL / NXCD)    // 136

typedef __bf16 bf16x8_t __attribute__((ext_vector_type(8)));
typedef float  f32x4_t  __attribute__((ext_vector_type(4)));

// LDS: A only, dbuf 2 x 16384 (128 rows x 128B fp32; source-preswizzled (row&7))
// 32 KB total. B never touches LDS (direct global bf16 fragment loads).
#define ABUF(i) ((i) * 16384)
#define LDS_BYTES 32768

#define WAITV0() asm volatile("s_waitcnt vmcnt(0)" ::: "memory")
#define SB() __builtin_amdgcn_sched_barrier(0)

// ws layout: ws[0] = ntiles; tile table (int4) at ws+4; bf16 weight at +32KB
#define WBF_OFF 32768

__global__ void setup_tiles(const int* __restrict__ cnt, int* __restrict__ ws) {
    int e = threadIdx.x;
    if (e >= NE) return;
    int off = 0, tbase = 0;
    for (int i = 0; i < e; ++i) {
        int c = cnt[i];
        off += c;
        tbase += (c + (BM - 1)) / BM;
    }
    int c = cnt[e];
    int nt = (c + (BM - 1)) / BM;
    int* tbl = ws + 4;
    for (int t = 0; t < nt; ++t) {
        int idx = tbase + t;
        tbl[4 * idx + 0] = e;
        tbl[4 * idx + 1] = off + t * BM;
        tbl[4 * idx + 2] = off + c;
        tbl[4 * idx + 3] = 0;
    }
    if (e == NE - 1) ws[0] = tbase + nt;
}

// weight fp32 -> bf16, streaming
__global__ __launch_bounds__(256) void wcvt(const float* __restrict__ w,
                                            __bf16* __restrict__ wbf) {
    const size_t stride = (size_t)gridDim.x * 256;
    size_t i = (size_t)blockIdx.x * 256 + threadIdx.x;
    const size_t n8 = (size_t)NE * DOUT * DIN / 8;
    for (; i < n8; i += stride) {
        f32x4_t a = *(const f32x4_t*)(w + i * 8);
        f32x4_t b = *(const f32x4_t*)(w + i * 8 + 4);
        bf16x8_t h;
#pragma unroll
        for (int j = 0; j < 4; ++j) {
            h[j]     = (__bf16)a[j];
            h[4 + j] = (__bf16)b[j];
        }
        *(bf16x8_t*)(wbf + i * 8) = h;
    }
}

__device__ __forceinline__ void gload16(const void* g, uint8_t* l) {
    __builtin_amdgcn_global_load_lds(
        (const __attribute__((address_space(1))) uint32_t*)g,
        (__attribute__((address_space(3))) uint32_t*)l, 16, 0, 0);
}

__global__ __launch_bounds__(512, 4) void moe_gemm(
    const float* __restrict__ inp,
    const __bf16* __restrict__ wbf,
    const float* __restrict__ bias,
    const int* __restrict__ ws,
    float* __restrict__ out)
{
    __shared__ __align__(16) uint8_t smem[LDS_BYTES];

    const int bid  = blockIdx.x;
    const int xcd  = bid & (NXCD - 1);
    const int slot = bid >> 3;                 // 0..271
    const int tile = xcd * TPX + (slot >> 1);
    const int n0   = (slot & 1) * BN;

    const int ntiles = ws[0];
    if (tile >= ntiles) return;
    const int4 ti = ((const int4*)(ws + 4))[tile];
    const int e = ti.x, row0 = ti.y, row_end = ti.z;

    const int tid  = threadIdx.x;
    const int lane = tid & 63;
    const int wave = tid >> 6;         // 0..7
    const int dr = lane >> 3;          // row-in-8-group
    const int ac = lane & 7;           // dest 16B chunk (linear)
    const int u  = ac ^ dr;            // logical chunk (group base % 8 == 0)

    // ---- A staging: 2 gload16/thread-wave, 8 rows x 128B each, preswizzled ----
    const float* asrc[2];
#pragma unroll
    for (int i = 0; i < 2; ++i) {
        int arow = wave * 16 + i * 8 + dr;
        int grow = row0 + arow;
        if (grow > row_end - 1) grow = row_end - 1;   // clamp (C-stores guarded)
        asrc[i] = inp + (size_t)grow * DIN + (u << 2);
    }
    auto issueA = [&](int t, int buf) {
        uint8_t* dst = smem + ABUF(buf) + wave * 2048;
#pragma unroll
        for (int i = 0; i < 2; ++i)
            gload16(asrc[i] + t * BK, dst + i * 1024);
    };

    // ---- compute geometry: wave owns 64 rows x 64 cols (4 x 4 frags) ----
    const int wr = (wave >> 2) * 64;   // 2 M-bands of 64
    const int wc = (wave & 3) * 64;    // 4 N-bands of 64
    const int frow = lane & 15;
    const int kg   = lane >> 4;

    // ---- B: direct global bf16 fragment pointers (L2-hot expert panel).
    // Fragment row = output col (n0+wc+n*16+frow), k-chunk = kg*8 elements.
    // Per step t: 16B load at +t*64B (imm-offset foldable, t*64 < 4096). ----
    const __bf16* bfrag[4];
#pragma unroll
    for (int n = 0; n < 4; ++n)
        bfrag[n] = wbf + (size_t)(e * DOUT + n0 + wc + n * 16 + frow) * DIN + kg * 8;

    f32x4_t acc[4][4] = {};

    bf16x8_t bg[4];
    auto loadB = [&](int t) {
#pragma unroll
        for (int n = 0; n < 4; ++n)
            bg[n] = *(const bf16x8_t*)(bfrag[n] + t * BK);
    };

    auto compute = [&](int buf) {
        bf16x8_t af[4];
#pragma unroll
        for (int m = 0; m < 4; ++m) {
            const int row = wr + m * 16 + frow;
            const uint8_t* pa = smem + ABUF(buf) + row * 128;
            const int sw = (row & 7) << 4;
            f32x4_t q0 = *(const f32x4_t*)(pa + ((kg * 32)      ^ sw));
            f32x4_t q1 = *(const f32x4_t*)(pa + ((kg * 32 + 16) ^ sw));
#pragma unroll
            for (int j = 0; j < 4; ++j) {
                af[m][j]     = (__bf16)q0[j];
                af[m][4 + j] = (__bf16)q1[j];
            }
        }
        __builtin_amdgcn_s_setprio(1);
#pragma unroll
        for (int m = 0; m < 4; ++m)
#pragma unroll
            for (int n = 0; n < 4; ++n)
                acc[m][n] = __builtin_amdgcn_mfma_f32_16x16x32_bf16(
                    af[m], bg[n], acc[m][n], 0, 0, 0);
        __builtin_amdgcn_s_setprio(0);
    };

    // ---- 2-phase A-dbuf loop. Issue order per step: loadB (4 vmem, oldest)
    // -> issueA(t+1) (2 DMA, newest). MFMA's auto-wait for bg is vmcnt(2),
    // which keeps the A DMA in flight; end-of-step vmcnt(0) certifies A(t+1)
    // with ~a full compute phase of latency already absorbed. ----
    issueA(0, 0);
    WAITV0(); SB();
    __builtin_amdgcn_s_barrier();
#pragma unroll
    for (int t = 0; t < NK; ++t) {
        const int buf = t & 1;
        loadB(t);
        SB();
        if (t + 1 < NK) issueA(t + 1, buf ^ 1);
        SB();
        compute(buf);
        if (t + 1 < NK) {
            WAITV0(); SB();
            __builtin_amdgcn_s_barrier();
        }
    }

    // ---- epilogue: C/D layout col = lane&15, row = (lane>>4)*4 + j [m89] ----
    const int crow = kg * 4;
    const int ccol = frow;
    float bv[4];
#pragma unroll
    for (int n = 0; n < 4; ++n)
        bv[n] = bias[e * DOUT + n0 + wc + n * 16 + ccol];
#pragma unroll
    for (int m = 0; m < 4; ++m) {
#pragma unroll
        for (int j = 0; j < 4; ++j) {
            const int grow = row0 + wr + m * 16 + crow + j;
            if (grow < row_end) {
                float* orow = out + (size_t)grow * DOUT + n0 + wc + ccol;
#pragma unroll
                for (int n = 0; n < 4; ++n)
                    orow[n * 16] = acc[m][n][j] + bv[n];
            }
        }
    }
}

extern "C" void kernel_launch(void* const* d_in, const int* in_sizes, int n_in,
                              void* d_out, int out_size, void* d_ws, size_t ws_size,
                              hipStream_t stream) {
    const float* inp    = (const float*)d_in[0];
    const float* weight = (const float*)d_in[1];
    const float* bias   = (const float*)d_in[2];
    const int* cnt      = (const int*)d_in[3];   // int64 in reference, delivered as int32
    float* out = (float*)d_out;
    int* ws = (int*)d_ws;
    __bf16* wbf = (__bf16*)((char*)d_ws + WBF_OFF);

    hipLaunchKernelGGL(setup_tiles, dim3(1), dim3(64), 0, stream, cnt, ws);
    hipLaunchKernelGGL(wcvt, dim3(2048), dim3(256), 0, stream, weight, wbf);
    hipLaunchKernelGGL(moe_gemm, dim3(TILES_TOTAL * 2), dim3(512), 0, stream,
                       inp, wbf, bias, ws, out);
}

// Round 12
// 205.830 us; speedup vs baseline: 1.3753x; 1.3753x over previous
//
#include <hip/hip_runtime.h>
#include <hip/hip_bf16.h>
#include <stdint.h>

#define NE    64
#define DIN   512
#define DOUT  512
#define TTOK  131072
#define BM    128
#define BN    256
#define BK    32
#define NK    (DIN / BK)              // 16 K-steps
#define TILES_TOTAL (TTOK / BM + NE)  // 1088
#define NXCD  8
#define TPX   (TILES_TOTAL / NXCD)    // 136

typedef __bf16 bf16x8_t __attribute__((ext_vector_type(8)));
typedef float  f32x4_t  __attribute__((ext_vector_type(4)));

// LDS (48 KB -> LDS-room for 3, regs cap 2 blocks/CU = 16 waves):
//   A dbuf: 2 x 8192   (64 LDS rows x 128B bf16; row lr holds A-rows lr & lr+64)
//   B dbuf: 2 x 16384  (128 LDS rows x 128B bf16; row lr holds dout lr & lr+128)
// Both use the proven (lr&7)<<4 XOR swizzle over 128B rows (2-way max).
#define ABUF(i) ((i) * 8192)
#define BBUF(i) (16384 + (i) * 16384)
#define LDS_BYTES 49152

#define WAITV0() asm volatile("s_waitcnt vmcnt(0)" ::: "memory")
#define LGKM0()  asm volatile("s_waitcnt lgkmcnt(0)" ::: "memory")
#define SB() __builtin_amdgcn_sched_barrier(0)

// ws layout: ws[0] = ntiles; tile table (int4) at ws+4; bf16 weight at +32KB
#define WBF_OFF 32768

__global__ void setup_tiles(const int* __restrict__ cnt, int* __restrict__ ws) {
    int e = threadIdx.x;
    if (e >= NE) return;
    int off = 0, tbase = 0;
    for (int i = 0; i < e; ++i) {
        int c = cnt[i];
        off += c;
        tbase += (c + (BM - 1)) / BM;
    }
    int c = cnt[e];
    int nt = (c + (BM - 1)) / BM;
    int* tbl = ws + 4;
    for (int t = 0; t < nt; ++t) {
        int idx = tbase + t;
        tbl[4 * idx + 0] = e;
        tbl[4 * idx + 1] = off + t * BM;
        tbl[4 * idx + 2] = off + c;
        tbl[4 * idx + 3] = 0;
    }
    if (e == NE - 1) ws[0] = tbase + nt;
}

// weight fp32 -> bf16, streaming
__global__ __launch_bounds__(256) void wcvt(const float* __restrict__ w,
                                            __bf16* __restrict__ wbf) {
    const size_t stride = (size_t)gridDim.x * 256;
    size_t i = (size_t)blockIdx.x * 256 + threadIdx.x;
    const size_t n8 = (size_t)NE * DOUT * DIN / 8;
    for (; i < n8; i += stride) {
        f32x4_t a = *(const f32x4_t*)(w + i * 8);
        f32x4_t b = *(const f32x4_t*)(w + i * 8 + 4);
        bf16x8_t h;
#pragma unroll
        for (int j = 0; j < 4; ++j) {
            h[j]     = (__bf16)a[j];
            h[4 + j] = (__bf16)b[j];
        }
        *(bf16x8_t*)(wbf + i * 8) = h;
    }
}

__device__ __forceinline__ void gload16(const void* g, uint8_t* l) {
    __builtin_amdgcn_global_load_lds(
        (const __attribute__((address_space(1))) uint32_t*)g,
        (__attribute__((address_space(3))) uint32_t*)l, 16, 0, 0);
}

__global__ __launch_bounds__(512, 4) void moe_gemm(
    const float* __restrict__ inp,
    const __bf16* __restrict__ wbf,
    const float* __restrict__ bias,
    const int* __restrict__ ws,
    float* __restrict__ out)
{
    __shared__ __align__(16) uint8_t smem[LDS_BYTES];

    const int bid  = blockIdx.x;
    const int xcd  = bid & (NXCD - 1);
    const int slot = bid >> 3;                 // 0..271
    const int tile = xcd * TPX + (slot >> 1);
    const int n0   = (slot & 1) * BN;

    const int ntiles = ws[0];
    if (tile >= ntiles) return;
    const int4 ti = ((const int4*)(ws + 4))[tile];
    const int e = ti.x, row0 = ti.y, row_end = ti.z;

    const int tid  = threadIdx.x;
    const int lane = tid & 63;
    const int wave = tid >> 6;         // 0..7
    const int dr = lane >> 3;          // row-in-8-group (DMA dest)
    const int ac = lane & 7;           // dest 16B chunk (linear)
    const int u  = ac ^ dr;            // logical chunk (group base % 8 == 0)

    // ---- B staging (R10-proven): 2 gload16/wave into 128-row paired layout.
    // LDS row lr (0..127), logical chunk u: u<4 -> dout n0+lr, k-part u&3;
    // u>=4 -> dout n0+lr+128. Source pre-swizzled so linear DMA dest works. ----
    const __bf16* bsrc[2];
#pragma unroll
    for (int i = 0; i < 2; ++i) {
        int lr = wave * 16 + i * 8 + dr;
        int dout = n0 + lr + ((u >> 2) << 7);
        bsrc[i] = wbf + (size_t)(e * DOUT + dout) * DIN + (u & 3) * 8;
    }
    auto issueB = [&](int t, int buf) {
        uint8_t* dst = smem + BBUF(buf) + wave * 2048;
#pragma unroll
        for (int i = 0; i < 2; ++i)
            gload16(bsrc[i] + t * BK, dst + i * 1024);
    };

    // ---- A staging: reg fp32 -> bf16 -> one swizzled ds_write_b128/thread.
    // 64-row paired layout: LDS row alr (0..63) chunk c: c<4 -> A-row alr
    // (k-part c&3), c>=4 -> A-row alr+64. Write byte = (c*16)^((alr&7)<<4). ----
    const int alr = tid >> 3;          // 0..63
    const int acn = tid & 7;           // chunk 0..7
    int agrow = row0 + alr + ((acn >> 2) << 6);
    if (agrow > row_end - 1) agrow = row_end - 1;   // clamp (C-stores guarded)
    const float* asrc = inp + (size_t)agrow * DIN + (acn & 3) * 8;
    const int awoff = alr * 128 + ((acn * 16) ^ ((alr & 7) << 4));

    f32x4_t ra[2];
    auto loadA = [&](int t) {
        ra[0] = *(const f32x4_t*)(asrc + t * BK);
        ra[1] = *(const f32x4_t*)(asrc + t * BK + 4);
    };
    auto writeA = [&](int buf) {
        bf16x8_t h;
#pragma unroll
        for (int j = 0; j < 4; ++j) {
            h[j]     = (__bf16)ra[0][j];
            h[4 + j] = (__bf16)ra[1][j];
        }
        *(bf16x8_t*)(smem + ABUF(buf) + awoff) = h;
    };

    // ---- compute: wave owns 64 rows x 64 cols (4 x 4 frags), all-bf16 LDS ----
    const int wr = (wave >> 2) * 64;   // 2 M-bands of 64
    const int wc = (wave & 3) * 64;    // 4 N-bands of 64
    const int frow = lane & 15;
    const int kg   = lane >> 4;

    f32x4_t acc[4][4] = {};

    auto compute = [&](int buf) {
        bf16x8_t af[4], bg[4];
#pragma unroll
        for (int m = 0; m < 4; ++m) {
            const int row = wr + m * 16 + frow;     // A-row in tile (0..127)
            const int lr  = row & 63;
            const int h   = row >> 6;
            af[m] = *(const bf16x8_t*)(smem + ABUF(buf) + lr * 128 +
                                       ((h * 64 + kg * 16) ^ ((lr & 7) << 4)));
        }
#pragma unroll
        for (int n = 0; n < 4; ++n) {
            const int row = wc + n * 16 + frow;     // dout-row in tile (0..255)
            const int lr  = row & 127;
            const int h   = row >> 7;
            bg[n] = *(const bf16x8_t*)(smem + BBUF(buf) + lr * 128 +
                                       ((h * 64 + kg * 16) ^ ((lr & 7) << 4)));
        }
        __builtin_amdgcn_s_setprio(1);
#pragma unroll
        for (int m = 0; m < 4; ++m)
#pragma unroll
            for (int n = 0; n < 4; ++n)
                acc[m][n] = __builtin_amdgcn_mfma_f32_16x16x32_bf16(
                    af[m], bg[n], acc[m][n], 0, 0, 0);
        __builtin_amdgcn_s_setprio(0);
    };

    // ---- 2-phase dbuf loop. Per step t: issue A-glb(t+1) + B-DMA(t+1),
    // compute(t), then cvt+ds_write A(t+1) (auto-wait = vmcnt(2): A loads are
    // older than the 2 B DMAs -> B stays in flight through the cvt), then
    // vmcnt(0) certifies B, lgkmcnt(0) publishes the ds_write, barrier. ----
    loadA(0);
    issueB(0, 0);
    writeA(0);                       // auto vmcnt(2): waits ra, B flies
    WAITV0(); LGKM0(); SB();
    __builtin_amdgcn_s_barrier();
#pragma unroll
    for (int t = 0; t < NK; ++t) {
        const int buf = t & 1;
        if (t + 1 < NK) {
            loadA(t + 1);
            SB();
            issueB(t + 1, buf ^ 1);
            SB();
        }
        compute(buf);
        if (t + 1 < NK) {
            writeA(buf ^ 1);         // buf^1 readers all passed barrier(t-1)
            WAITV0(); LGKM0(); SB();
            __builtin_amdgcn_s_barrier();
        }
    }

    // ---- epilogue: C/D layout col = lane&15, row = (lane>>4)*4 + j [m89] ----
    const int crow = kg * 4;
    const int ccol = frow;
    float bv[4];
#pragma unroll
    for (int n = 0; n < 4; ++n)
        bv[n] = bias[e * DOUT + n0 + wc + n * 16 + ccol];
#pragma unroll
    for (int m = 0; m < 4; ++m) {
#pragma unroll
        for (int j = 0; j < 4; ++j) {
            const int grow = row0 + wr + m * 16 + crow + j;
            if (grow < row_end) {
                float* orow = out + (size_t)grow * DOUT + n0 + wc + ccol;
#pragma unroll
                for (int n = 0; n < 4; ++n)
                    orow[n * 16] = acc[m][n][j] + bv[n];
            }
        }
    }
}

extern "C" void kernel_launch(void* const* d_in, const int* in_sizes, int n_in,
                              void* d_out, int out_size, void* d_ws, size_t ws_size,
                              hipStream_t stream) {
    const float* inp    = (const float*)d_in[0];
    const float* weight = (const float*)d_in[1];
    const float* bias   = (const float*)d_in[2];
    const int* cnt      = (const int*)d_in[3];   // int64 in reference, delivered as int32
    float* out = (float*)d_out;
    int* ws = (int*)d_ws;
    __bf16* wbf = (__bf16*)((char*)d_ws + WBF_OFF);

    hipLaunchKernelGGL(setup_tiles, dim3(1), dim3(64), 0, stream, cnt, ws);
    hipLaunchKernelGGL(wcvt, dim3(2048), dim3(256), 0, stream, weight, wbf);
    hipLaunchKernelGGL(moe_gemm, dim3(TILES_TOTAL * 2), dim3(512), 0, stream,
                       inp, wbf, bias, ws, out);
}